// Round 9
// baseline (619.454 us; speedup 1.0000x reference)
//
#include <hip/hip_runtime.h>
#include <hip/hip_bf16.h>
#include <math.h>

// Problem constants
#define B_   2
#define N_   8192
#define DM   768
#define NH   12
#define HD   64

// Workspace layout:
//   Qh (f16) at byte 0, Ql after it; OLN fp32 reuses the region later.
//   AC at float 12,582,912, SUMS at float 19,922,944
#define QL_ELEM_OFF 12582912ull
#define AC_OFF      12582912ull
#define SUMS_OFF    19922944ull

typedef short bf16x8 __attribute__((ext_vector_type(8)));
typedef _Float16 f16x8 __attribute__((ext_vector_type(8)));
typedef _Float16 f16x4 __attribute__((ext_vector_type(4)));
typedef float f32x4  __attribute__((ext_vector_type(4)));

__device__ __forceinline__ size_t ac_base(int grp) {
    return 8388608ull - (8388608ull >> grp);
}

__device__ __forceinline__ unsigned short f2bf(float f) {
    __hip_bfloat16 h = __float2bfloat16(f);
    return __builtin_bit_cast(unsigned short, h);
}
__device__ __forceinline__ float bf2f(unsigned short u) {
    __hip_bfloat16 h = __builtin_bit_cast(__hip_bfloat16, u);
    return __bfloat162float(h);
}
// fp16 RNE split: f ~= hi + lo with |f - hi - lo| <= 2^-22 |f|.
__device__ __forceinline__ void split2h(float f, _Float16& h, _Float16& l) {
    h = (_Float16)f;
    l = (_Float16)(f - (float)h);
}

// XOR-chunk swizzle for 2-byte arrays, pitch 64 elements (128 B row).
#define SW(row, col) ((((row) << 6)) + ((((col) >> 3) ^ ((row) & 7)) << 3) + ((col) & 7))

// ---------------------------------------------------------------------------
// Split-bf16 MFMA GEMM (NT). If Ch != nullptr, epilogue writes the result as
// an fp16 RNE hi/lo split (for the attention kernel); else fp32 to C.
// (validated R3/R7 structure, unchanged)
// ---------------------------------------------------------------------------
__global__ __launch_bounds__(256) void gemm_mfma_split(
    const float* __restrict__ A, const float* __restrict__ W,
    const float* __restrict__ bias, float* __restrict__ C,
    _Float16* __restrict__ Ch, _Float16* __restrict__ Cl) {
    __shared__ unsigned short AsH[128][40];
    __shared__ unsigned short AsL[128][40];
    __shared__ unsigned short WsH[128][40];
    __shared__ unsigned short WsL[128][40];

    const int t    = threadIdx.x;
    const int lane = t & 63;
    const int wv   = t >> 6;
    const int c    = lane & 15, q = lane >> 4;
    const int mw   = (wv & 1) * 64, nw = (wv >> 1) * 64;
    const int m0   = blockIdx.x * 128, n0 = blockIdx.y * 128;

    const int srow = t >> 1;
    const int scol = (t & 1) * 16;
    const float* ap = A + (size_t)(m0 + srow) * DM + scol;
    const float* wp = W + (size_t)(n0 + srow) * DM + scol;

    f32x4 acc[4][4];
#pragma unroll
    for (int mi = 0; mi < 4; ++mi)
#pragma unroll
        for (int ni = 0; ni < 4; ++ni) {
            acc[mi][ni][0] = 0.f; acc[mi][ni][1] = 0.f;
            acc[mi][ni][2] = 0.f; acc[mi][ni][3] = 0.f;
        }

    for (int k0 = 0; k0 < DM; k0 += 32) {
        float av[16], wvv[16];
        *(float4*)&av[0]  = *(const float4*)(ap + k0);
        *(float4*)&av[4]  = *(const float4*)(ap + k0 + 4);
        *(float4*)&av[8]  = *(const float4*)(ap + k0 + 8);
        *(float4*)&av[12] = *(const float4*)(ap + k0 + 12);
        *(float4*)&wvv[0]  = *(const float4*)(wp + k0);
        *(float4*)&wvv[4]  = *(const float4*)(wp + k0 + 4);
        *(float4*)&wvv[8]  = *(const float4*)(wp + k0 + 8);
        *(float4*)&wvv[12] = *(const float4*)(wp + k0 + 12);
        __syncthreads();
#pragma unroll
        for (int i = 0; i < 16; ++i) {
            const float x = av[i];
            const unsigned short xh = f2bf(x);
            AsH[srow][scol + i] = xh;
            AsL[srow][scol + i] = f2bf(x - bf2f(xh));
            const float y = wvv[i];
            const unsigned short yh = f2bf(y);
            WsH[srow][scol + i] = yh;
            WsL[srow][scol + i] = f2bf(y - bf2f(yh));
        }
        __syncthreads();

        bf16x8 ah[4], al[4], bh[4], bl[4];
#pragma unroll
        for (int i = 0; i < 4; ++i) {
            ah[i] = *(const bf16x8*)&AsH[mw + i*16 + c][q*8];
            al[i] = *(const bf16x8*)&AsL[mw + i*16 + c][q*8];
            bh[i] = *(const bf16x8*)&WsH[nw + i*16 + c][q*8];
            bl[i] = *(const bf16x8*)&WsL[nw + i*16 + c][q*8];
        }
#pragma unroll
        for (int mi = 0; mi < 4; ++mi)
#pragma unroll
            for (int ni = 0; ni < 4; ++ni) {
                f32x4 v = acc[mi][ni];
                v = __builtin_amdgcn_mfma_f32_16x16x32_bf16(ah[mi], bl[ni], v, 0, 0, 0);
                v = __builtin_amdgcn_mfma_f32_16x16x32_bf16(al[mi], bh[ni], v, 0, 0, 0);
                v = __builtin_amdgcn_mfma_f32_16x16x32_bf16(ah[mi], bh[ni], v, 0, 0, 0);
                acc[mi][ni] = v;
            }
    }

#pragma unroll
    for (int ni = 0; ni < 4; ++ni) {
        const int col = n0 + nw + ni*16 + c;
        const float bv = bias[col];
#pragma unroll
        for (int mi = 0; mi < 4; ++mi)
#pragma unroll
            for (int r = 0; r < 4; ++r) {
                const int row = m0 + mw + mi*16 + q*4 + r;
                const float val = acc[mi][ni][r] + bv;
                if (Ch) {
                    _Float16 hh, ll;
                    split2h(val, hh, ll);
                    Ch[(size_t)row * DM + col] = hh;
                    Cl[(size_t)row * DM + col] = ll;
                } else {
                    C[(size_t)row * DM + col] = val;
                }
            }
    }
}

// ---------------------------------------------------------------------------
// Split-FP16 MFMA flash attention, S^T orientation, 128-query blocks,
// TWO waves of 128 threads; each wave owns 64 queries as four 16-col tiles
// (jt). K/V^T tile reads amortized over 4 jt (the binding LDS-BW knob).
// LDS: K/VT 32 KB + P^T 32 KB = 64 KB -> 2 blocks/CU.
// ---------------------------------------------------------------------------
__global__ __launch_bounds__(128, 2) void attn_mfma_kernel(
    const _Float16* __restrict__ Qh, const _Float16* __restrict__ Ql,
    float* __restrict__ AC) {
    __shared__ __align__(16) _Float16 KH[4096],  KL[4096];   // K [key][d]
    __shared__ __align__(16) _Float16 VTH[4096], VTL[4096];  // K^T [d][key]
    __shared__ __align__(16) _Float16 PTH[8192], PTL[8192];  // P^T [q(128)][k(64)]

    const int t    = threadIdx.x;
    const int lane = t & 63;
    const int w    = t >> 6;           // 0..1
    const int c    = lane & 15, quad = lane >> 4;

    // block -> (grp, b, seg, head, 128-q tile)
    const int bi  = blockIdx.x;
    const int qt  = bi & 15;
    const int bsh = bi >> 4;
    int grp, local;
    if (bsh < 32)      { grp = 0; local = bsh; }
    else if (bsh < 48) { grp = 1; local = bsh - 32; }
    else               { grp = 2; local = bsh - 48; }
    const int nseg = 4 >> grp;
    const int sseg = 2048 << grp;
    const int r    = 1 << grp;
    const int b    = local / (nseg * 4);
    const int rem  = local - b * nseg * 4;
    const int seg  = rem >> 2;
    const int hg   = rem & 3;
    const int head = grp * 4 + hg;

    const size_t row0 = (size_t)(b * N_ + seg * sseg + grp);
    const int hoff = head * HD;

    const int r0 = (t >> 4) * 8;   // staging rows (keys) 0..56, 8 rows/thread
    const int c0 = (t & 15) * 4;   // staging cols (d)    0..60

    // ---- Q B-frags (loop-invariant): queries qt*128 + w*64 + jt*16 + c ----
    f16x8 qfh[4][2], qfl[4][2];   // [jt][kc]
#pragma unroll
    for (int jt = 0; jt < 4; ++jt) {
        const int qrow = qt*128 + w*64 + jt*16 + c;
        const size_t qoff = (row0 + (size_t)qrow * r) * DM + hoff;
#pragma unroll
        for (int kc = 0; kc < 2; ++kc) {
            f16x8 h = *(const f16x8*)(Qh + qoff + kc*32 + quad*8);
            f16x8 l = *(const f16x8*)(Ql + qoff + kc*32 + quad*8);
            qfh[jt][kc] = h * (_Float16)0.125f;   // fold 1/sqrt(64), exact pow2
            qfl[jt][kc] = l * (_Float16)0.125f;
        }
    }

    // ---- stage K-tile 0 ----
    {
        f16x4 hh[8], ll[8];
#pragma unroll
        for (int i = 0; i < 8; ++i) {
            const size_t off = (row0 + (size_t)(r0 + i) * r) * DM + hoff + c0;
            hh[i] = *(const f16x4*)(Qh + off);
            ll[i] = *(const f16x4*)(Ql + off);
        }
#pragma unroll
        for (int i = 0; i < 8; ++i) {
            *(f16x4*)&KH[SW(r0 + i, c0)] = hh[i];
            *(f16x4*)&KL[SW(r0 + i, c0)] = ll[i];
        }
#pragma unroll
        for (int j = 0; j < 4; ++j) {
            *(f16x4*)&VTH[SW(c0 + j, r0)]     = (f16x4){hh[0][j], hh[1][j], hh[2][j], hh[3][j]};
            *(f16x4*)&VTH[SW(c0 + j, r0 + 4)] = (f16x4){hh[4][j], hh[5][j], hh[6][j], hh[7][j]};
            *(f16x4*)&VTL[SW(c0 + j, r0)]     = (f16x4){ll[0][j], ll[1][j], ll[2][j], ll[3][j]};
            *(f16x4*)&VTL[SW(c0 + j, r0 + 4)] = (f16x4){ll[4][j], ll[5][j], ll[6][j], ll[7][j]};
        }
    }
    __syncthreads();

    float m_st[4] = {-1e30f, -1e30f, -1e30f, -1e30f};
    float l_st[4] = {0.f, 0.f, 0.f, 0.f};
    f32x4 o[4][4];
#pragma unroll
    for (int jt = 0; jt < 4; ++jt)
#pragma unroll
        for (int i = 0; i < 4; ++i) {
            o[jt][i][0] = 0.f; o[jt][i][1] = 0.f;
            o[jt][i][2] = 0.f; o[jt][i][3] = 0.f;
        }

    for (int kt = 0; kt < 32; ++kt) {
        // prefetch next K-tile into registers
        f16x4 nh[8], nl[8];
        if (kt < 31) {
#pragma unroll
            for (int i = 0; i < 8; ++i) {
                const size_t off = (row0 + (size_t)((kt+1)*64 + r0 + i) * r) * DM + hoff + c0;
                nh[i] = *(const f16x4*)(Qh + off);
                nl[i] = *(const f16x4*)(Ql + off);
            }
        }

        // ---- S^T[k][q]: A = K rows (shared across jt), B = Q^T ----
        f32x4 s[4][4];
#pragma unroll
        for (int jt = 0; jt < 4; ++jt)
#pragma unroll
            for (int mt = 0; mt < 4; ++mt) {
                s[jt][mt][0] = 0.f; s[jt][mt][1] = 0.f;
                s[jt][mt][2] = 0.f; s[jt][mt][3] = 0.f;
            }
#pragma unroll
        for (int kc = 0; kc < 2; ++kc)
#pragma unroll
            for (int mt = 0; mt < 4; ++mt) {
                f16x8 ah = *(const f16x8*)&KH[SW(mt*16 + c, kc*32 + quad*8)];
                f16x8 al = *(const f16x8*)&KL[SW(mt*16 + c, kc*32 + quad*8)];
#pragma unroll
                for (int jt = 0; jt < 4; ++jt) {
                    f32x4 v = s[jt][mt];
                    v = __builtin_amdgcn_mfma_f32_16x16x32_f16(ah, qfl[jt][kc], v, 0, 0, 0);
                    v = __builtin_amdgcn_mfma_f32_16x16x32_f16(al, qfh[jt][kc], v, 0, 0, 0);
                    v = __builtin_amdgcn_mfma_f32_16x16x32_f16(ah, qfh[jt][kc], v, 0, 0, 0);
                    s[jt][mt] = v;
                }
            }

        // ---- per-lane online softmax (independent per jt) + P^T write ----
#pragma unroll
        for (int jt = 0; jt < 4; ++jt) {
            float mloc = s[jt][0][0];
#pragma unroll
            for (int mt = 0; mt < 4; ++mt)
#pragma unroll
                for (int rg = 0; rg < 4; ++rg) mloc = fmaxf(mloc, s[jt][mt][rg]);
            mloc = fmaxf(mloc, __shfl_xor(mloc, 16));
            mloc = fmaxf(mloc, __shfl_xor(mloc, 32));
            const float mnew  = fmaxf(m_st[jt], mloc);
            const float alpha = __expf(m_st[jt] - mnew);
            m_st[jt] = mnew;

            float psum = 0.f;
            const int prow = w*64 + jt*16 + c;
#pragma unroll
            for (int mt = 0; mt < 4; ++mt) {
                f16x4 hh, ll;
#pragma unroll
                for (int rg = 0; rg < 4; ++rg) {
                    const float pv = __expf(s[jt][mt][rg] - mnew);
                    psum += pv;
                    _Float16 th, tl;
                    split2h(pv, th, tl);
                    hh[rg] = th;
                    ll[rg] = tl;
                }
                *(f16x4*)&PTH[SW(prow, mt*16 + quad*4)] = hh;
                *(f16x4*)&PTL[SW(prow, mt*16 + quad*4)] = ll;
            }
            psum += __shfl_xor(psum, 16);
            psum += __shfl_xor(psum, 32);
            l_st[jt] = l_st[jt] * alpha + psum;
#pragma unroll
            for (int mtd = 0; mtd < 4; ++mtd) {
                o[jt][mtd][0] *= alpha; o[jt][mtd][1] *= alpha;
                o[jt][mtd][2] *= alpha; o[jt][mtd][3] *= alpha;
            }
        }
        // wave-private P^T rows: same-wave write->read, no barrier needed

        // ---- PV: O^T[d][q] += V^T P^T (V^T frags shared across jt) ----
#pragma unroll
        for (int kc = 0; kc < 2; ++kc) {
            f16x8 ph[4], pl[4];
#pragma unroll
            for (int jt = 0; jt < 4; ++jt) {
                ph[jt] = *(const f16x8*)&PTH[SW(w*64 + jt*16 + c, kc*32 + quad*8)];
                pl[jt] = *(const f16x8*)&PTL[SW(w*64 + jt*16 + c, kc*32 + quad*8)];
            }
#pragma unroll
            for (int mtd = 0; mtd < 4; ++mtd) {
                f16x8 vh = *(const f16x8*)&VTH[SW(mtd*16 + c, kc*32 + quad*8)];
                f16x8 vl = *(const f16x8*)&VTL[SW(mtd*16 + c, kc*32 + quad*8)];
#pragma unroll
                for (int jt = 0; jt < 4; ++jt) {
                    f32x4 v = o[jt][mtd];
                    v = __builtin_amdgcn_mfma_f32_16x16x32_f16(vh, pl[jt], v, 0, 0, 0);
                    v = __builtin_amdgcn_mfma_f32_16x16x32_f16(vl, ph[jt], v, 0, 0, 0);
                    v = __builtin_amdgcn_mfma_f32_16x16x32_f16(vh, ph[jt], v, 0, 0, 0);
                    o[jt][mtd] = v;
                }
            }
        }

        // ---- stage prefetched tile ----
        if (kt < 31) {
            __syncthreads();   // both waves done reading KH/KL/VTH/VTL
#pragma unroll
            for (int i = 0; i < 8; ++i) {
                *(f16x4*)&KH[SW(r0 + i, c0)] = nh[i];
                *(f16x4*)&KL[SW(r0 + i, c0)] = nl[i];
            }
#pragma unroll
            for (int j = 0; j < 4; ++j) {
                *(f16x4*)&VTH[SW(c0 + j, r0)]     = (f16x4){nh[0][j], nh[1][j], nh[2][j], nh[3][j]};
                *(f16x4*)&VTH[SW(c0 + j, r0 + 4)] = (f16x4){nh[4][j], nh[5][j], nh[6][j], nh[7][j]};
                *(f16x4*)&VTL[SW(c0 + j, r0)]     = (f16x4){nl[0][j], nl[1][j], nl[2][j], nl[3][j]};
                *(f16x4*)&VTL[SW(c0 + j, r0 + 4)] = (f16x4){nl[4][j], nl[5][j], nl[6][j], nl[7][j]};
            }
            __syncthreads();
        }
    }

    // ---- epilogue: O^T C-layout -> AC rows ----
    const size_t gbase = ac_base(grp);
#pragma unroll
    for (int jt = 0; jt < 4; ++jt) {
        const float inv = 1.0f / l_st[jt];
        const int qrow = qt*128 + w*64 + jt*16 + c;
        float* dst = AC + gbase + ((size_t)((b*nseg + seg)*2048 + qrow)) * 256 + hg*64;
#pragma unroll
        for (int mtd = 0; mtd < 4; ++mtd) {
            float4 v = make_float4(o[jt][mtd][0]*inv, o[jt][mtd][1]*inv,
                                   o[jt][mtd][2]*inv, o[jt][mtd][3]*inv);
            *(float4*)(dst + mtd*16 + quad*4) = v;
        }
    }
}

// ---------------------------------------------------------------------------
// Per-(group,b,head-in-group,d) sums — 896 blocks x 32 positions (8x the
// parallelism of R8's 112-block version; was latency-bound).
// ---------------------------------------------------------------------------
__global__ __launch_bounds__(256) void sum_kernel(
    const float* __restrict__ AC, float* __restrict__ SUMS) {
    const int bi = blockIdx.x;
    int grp, local;
    if (bi < 512)      { grp = 0; local = bi; }
    else if (bi < 768) { grp = 1; local = bi - 512; }
    else               { grp = 2; local = bi - 768; }
    const int chunks = 256 >> grp;      // 32-position chunks per (grp,b)
    const int b  = local / chunks;
    const int ch = local - b * chunks;
    const int P  = 8192 >> grp;
    const size_t base = ac_base(grp) + ((size_t)b * P + ch * 32) * 256 + threadIdx.x;
    float acc = 0.f;
    for (int p = 0; p < 32; ++p) acc += AC[base + (size_t)p * 256];
    atomicAdd(&SUMS[((grp << 1) + b) * 256 + threadIdx.x], acc);
}

// ---------------------------------------------------------------------------
// Renormalize + scatter + /3 + LayerNorm — one WAVE per position (no LDS,
// no barriers; reductions via __shfl_xor over 64 lanes). 4 positions/block.
// Lane l handles d=l for all 12 heads (dm = jj*64 + l).
// ---------------------------------------------------------------------------
__global__ __launch_bounds__(256) void renorm_ln_kernel(
    const float* __restrict__ AC, const float* __restrict__ SUMS,
    const float* __restrict__ gamma, const float* __restrict__ beta,
    float* __restrict__ OLN) {
    const int pos = blockIdx.x * 4 + (threadIdx.x >> 6);
    const int l   = threadIdx.x & 63;
    const int b = pos >> 13;
    const int n = pos & 8191;

    float v[12];
#pragma unroll
    for (int jj = 0; jj < 12; ++jj) {
        const int grp = jj >> 2, hg = jj & 3;
        const int r = 1 << grp;
        const int p = n & ((2048 << grp) - 1);
        float val = 0.f;
        if ((p & (r - 1)) == grp) {
            const int nseg = 4 >> grp;
            const int seg  = n >> (11 + grp);
            const int j    = (p - grp) >> grp;
            const float s  = SUMS[((grp << 1) + b) * 256 + (hg << 6) + l];
            val = AC[ac_base(grp) + ((size_t)((b*nseg + seg)*2048 + j)) * 256 + (hg << 6) + l]
                  / (3.0f * s);
        }
        v[jj] = val;
    }

    float tot = 0.f;
#pragma unroll
    for (int jj = 0; jj < 12; ++jj) tot += v[jj];
#pragma unroll
    for (int o = 32; o > 0; o >>= 1) tot += __shfl_xor(tot, o);
    const float mu = tot * (1.0f / 768.0f);

    float sq = 0.f;
#pragma unroll
    for (int jj = 0; jj < 12; ++jj) {
        const float d0 = v[jj] - mu;
        sq += d0 * d0;
    }
#pragma unroll
    for (int o = 32; o > 0; o >>= 1) sq += __shfl_xor(sq, o);
    const float rstd = rsqrtf(sq * (1.0f / 768.0f) + 1e-5f);

    float* dst = OLN + (size_t)pos * 768;
#pragma unroll
    for (int jj = 0; jj < 12; ++jj) {
        const int dm = jj*64 + l;
        dst[dm] = (v[jj] - mu) * rstd * gamma[dm] + beta[dm];
    }
}

// ---------------------------------------------------------------------------
extern "C" void kernel_launch(void* const* d_in, const int* in_sizes, int n_in,
                              void* d_out, int out_size, void* d_ws, size_t ws_size,
                              hipStream_t stream) {
    const float* x     = (const float*)d_in[0];
    const float* w_in  = (const float*)d_in[1];
    const float* b_in  = (const float*)d_in[2];
    const float* w_out = (const float*)d_in[3];
    const float* b_out = (const float*)d_in[4];
    const float* gamma = (const float*)d_in[5];
    const float* beta  = (const float*)d_in[6];
    float* out = (float*)d_out;

    float* ws   = (float*)d_ws;
    _Float16* Qh = (_Float16*)ws;                 // fp16 hi, 12.58M elems
    _Float16* Ql = (_Float16*)ws + QL_ELEM_OFF;   // fp16 lo
    float* AC   = ws + AC_OFF;
    float* SUMS = ws + SUMS_OFF;
    float* OLN  = ws;   // reuses Qh/Ql region (dead after attention)

    // 1) Q = x @ w_in.T + b_in, written as fp16 hi/lo split
    gemm_mfma_split<<<dim3(128, 6), 256, 0, stream>>>(x, w_in, b_in, nullptr, Qh, Ql);
    // 2) dilated flash attention (split-fp16 MFMA, S^T, 2-wave 128-q blocks)
    attn_mfma_kernel<<<896, 128, 0, stream>>>(Qh, Ql, AC);
    // 3) per-(group,b,h,d) position sums
    (void)hipMemsetAsync(SUMS, 0, 1536 * sizeof(float), stream);
    sum_kernel<<<896, 256, 0, stream>>>(AC, SUMS);
    // 4) renorm + scatter + /3 + LayerNorm (wave-per-position)
    renorm_ln_kernel<<<B_ * N_ / 4, 256, 0, stream>>>(AC, SUMS, gamma, beta, OLN);
    // 5) out = OLN @ w_out.T + b_out (fp32 epilogue)
    gemm_mfma_split<<<dim3(128, 6), 256, 0, stream>>>(OLN, w_out, b_out, out,
                                                      nullptr, nullptr);
}